// Round 2
// baseline (385.930 us; speedup 1.0000x reference)
//
#include <hip/hip_runtime.h>
#include <math.h>

#define EMB 1024
#define NB 4
#define SQ 2048
#define TOK (NB*SQ)   // 8192

typedef __attribute__((ext_vector_type(8))) short bhalf8;   // 8 bf16 in 4 VGPRs
typedef __attribute__((ext_vector_type(4))) float f32x4;

__device__ __forceinline__ unsigned short f32_to_bf16(float f) {
    unsigned int u = __float_as_uint(f);
    u += 0x7FFFu + ((u >> 16) & 1u);       // round-to-nearest-even
    return (unsigned short)(u >> 16);
}
__device__ __forceinline__ float bf16_to_f32(unsigned short h) {
    return __uint_as_float(((unsigned int)h) << 16);
}

// ---------------- fp32 -> bf16 conversion (with optional scale) ----------------
__global__ __launch_bounds__(256) void convert_kernel(const float* __restrict__ src,
                                                      unsigned short* __restrict__ dst,
                                                      int n4, float scale) {
    int i = blockIdx.x * 256 + threadIdx.x;
    if (i >= n4) return;
    float4 v = ((const float4*)src)[i];
    ushort4 o;
    o.x = f32_to_bf16(v.x * scale);
    o.y = f32_to_bf16(v.y * scale);
    o.z = f32_to_bf16(v.z * scale);
    o.w = f32_to_bf16(v.w * scale);
    ((ushort4*)dst)[i] = o;
}

// ---------------- async global->LDS 16B staging helper ----------------
__device__ __forceinline__ void async_load16(const unsigned short* gp, unsigned short* lp) {
    __builtin_amdgcn_global_load_lds(
        (const __attribute__((address_space(1))) unsigned int*)gp,
        (__attribute__((address_space(3))) unsigned int*)lp,
        16, 0, 0);
}

// ---------------- NT GEMM: C[m,n] = sum_k A[m,k]*B[n,k], bf16 in, fp32 acc ----------------
// MODE 0: store bf16 C
// MODE 1: store fp32 C
// MODE 2: g = sigmoid(acc); read fp32 Ofp; Fout = g * Ofp   (final gated output)
// MODE 3: store bf16 C AND fp32 Fout (same values)
template <int MODE>
__global__ __launch_bounds__(256) void gemm_nt(
    const unsigned short* __restrict__ A,
    const unsigned short* __restrict__ B,
    void* __restrict__ C,
    const float* __restrict__ Ofp,
    float* __restrict__ Fout,
    int M, int N, int K, int lda, int ldb, int ldc,
    long sA, long sB, long sC)
{
    __shared__ __align__(16) unsigned short As[128*32];   // 8 KB, row-major, row stride 32
    __shared__ __align__(16) unsigned short Bs[128*32];

    const int bz = blockIdx.z;
    const unsigned short* Ab = A + (long)bz * sA;
    const unsigned short* Bb = B + (long)bz * sB;
    const int bm = blockIdx.x * 128;
    const int bn = blockIdx.y * 128;
    const int t = threadIdx.x;
    const int w = t >> 6;        // wave 0..3
    const int l = t & 63;        // lane
    const int srow = l >> 2;     // staging row within 16-row group
    const int scol = (l & 3) * 8;

    f32x4 zero = {0.f, 0.f, 0.f, 0.f};
    f32x4 acc[4][4];
    #pragma unroll
    for (int i = 0; i < 4; ++i)
        #pragma unroll
        for (int j = 0; j < 4; ++j) acc[i][j] = zero;

    const int wm = (w >> 1) * 64;   // wave's 64x64 sub-tile
    const int wn = (w & 1) * 64;
    const int fr = l & 15;          // fragment row/col
    const int kq = (l >> 4) * 8;    // fragment k offset

    const int nkt = K >> 5;
    for (int kt = 0; kt < nkt; ++kt) {
        const int k0 = kt << 5;
        __syncthreads();            // LDS consumers of previous tile done
        #pragma unroll
        for (int r = 0; r < 2; ++r) {
            const int rr = (r*4 + w) * 16 + srow;   // tile row 0..127
            // LDS dest: wave-uniform base + lane*16B == row-major (row*32+col) layout
            async_load16(Ab + (long)(bm + rr) * lda + (k0 + scol), As + (r*4 + w) * 512);
            async_load16(Bb + (long)(bn + rr) * ldb + (k0 + scol), Bs + (r*4 + w) * 512);
        }
        __syncthreads();            // vmcnt(0) drain: staging complete

        bhalf8 af[4], bfr[4];
        #pragma unroll
        for (int mi = 0; mi < 4; ++mi)
            af[mi] = *(const bhalf8*)(As + (wm + mi*16 + fr) * 32 + kq);
        #pragma unroll
        for (int ni = 0; ni < 4; ++ni)
            bfr[ni] = *(const bhalf8*)(Bs + (wn + ni*16 + fr) * 32 + kq);
        #pragma unroll
        for (int mi = 0; mi < 4; ++mi)
            #pragma unroll
            for (int ni = 0; ni < 4; ++ni)
                acc[mi][ni] = __builtin_amdgcn_mfma_f32_16x16x32_bf16(
                    af[mi], bfr[ni], acc[mi][ni], 0, 0, 0);
    }

    // C/D layout (m89-verified): col = lane&15, row = (lane>>4)*4 + reg
    const int crow = (l >> 4) * 4;
    const int ccol = l & 15;
    #pragma unroll
    for (int mi = 0; mi < 4; ++mi) {
        #pragma unroll
        for (int ni = 0; ni < 4; ++ni) {
            #pragma unroll
            for (int r = 0; r < 4; ++r) {
                const int gr = bm + wm + mi*16 + crow + r;
                const int gc = bn + wn + ni*16 + ccol;
                const float v = acc[mi][ni][r];
                const long idx = (long)gr * ldc + gc;
                if (MODE == 0) {
                    ((unsigned short*)C)[(long)bz*sC + idx] = f32_to_bf16(v);
                } else if (MODE == 1) {
                    ((float*)C)[(long)bz*sC + idx] = v;
                } else if (MODE == 2) {
                    const float o = Ofp[idx];
                    const float g = 1.0f / (1.0f + __expf(-v));
                    Fout[idx] = g * o;
                } else {
                    ((unsigned short*)C)[idx] = f32_to_bf16(v);
                    Fout[idx] = v;
                }
            }
        }
    }
}

// ---------------- row softmax: fp32 scores in, bf16 attn out (row len 2048) ----------------
__global__ __launch_bounds__(256) void softmax_kernel(const float* __restrict__ sc,
                                                      unsigned short* __restrict__ attn) {
    const long row = blockIdx.x;
    const float* p = sc + row * SQ;
    unsigned short* q = attn + row * SQ;
    const int t = threadIdx.x;
    const int w = t >> 6, l = t & 63;
    float4 a = ((const float4*)p)[2*t];
    float4 b = ((const float4*)p)[2*t + 1];
    float f[8] = {a.x, a.y, a.z, a.w, b.x, b.y, b.z, b.w};
    float m = -1e30f;
    #pragma unroll
    for (int j = 0; j < 8; ++j) m = fmaxf(m, f[j]);
    #pragma unroll
    for (int off = 32; off; off >>= 1) m = fmaxf(m, __shfl_xor(m, off));
    __shared__ float smax[4], ssum[4];
    if (l == 0) smax[w] = m;
    __syncthreads();
    m = fmaxf(fmaxf(smax[0], smax[1]), fmaxf(smax[2], smax[3]));
    float s = 0.f;
    #pragma unroll
    for (int j = 0; j < 8; ++j) { f[j] = __expf(f[j] - m); s += f[j]; }
    #pragma unroll
    for (int off = 32; off; off >>= 1) s += __shfl_xor(s, off);
    if (l == 0) ssum[w] = s;
    __syncthreads();
    const float inv = 1.0f / (ssum[0] + ssum[1] + ssum[2] + ssum[3]);
    union { bhalf8 v; unsigned short u[8]; } o;
    #pragma unroll
    for (int j = 0; j < 8; ++j) o.u[j] = f32_to_bf16(f[j] * inv);
    ((bhalf8*)q)[t] = o.v;
}

// ---------------- transpose v (per batch: (2048 x 1024, ld 3072) -> (1024 x 2048)) ----------------
__global__ void transpose_v(const unsigned short* __restrict__ qkv,
                            unsigned short* __restrict__ vT) {
    __shared__ unsigned short tile[32][33];
    const int b = blockIdx.z;
    const unsigned short* v = qkv + (long)b * SQ * (3*EMB) + 2*EMB;
    const int e = blockIdx.x * 32 + threadIdx.x;
    const int s = blockIdx.y * 32 + threadIdx.y;
    tile[threadIdx.y][threadIdx.x] = v[(long)s * (3*EMB) + e];
    __syncthreads();
    const int so = blockIdx.y * 32 + threadIdx.x;
    const int eo = blockIdx.x * 32 + threadIdx.y;
    vT[(long)b * EMB * SQ + (long)eo * SQ + so] = tile[threadIdx.x][threadIdx.y];
}

extern "C" void kernel_launch(void* const* d_in, const int* in_sizes, int n_in,
                              void* d_out, int out_size, void* d_ws, size_t ws_size,
                              hipStream_t stream) {
    const float* rot = (const float*)d_in[0];   // (3E, E) row-major
    const float* ent = (const float*)d_in[1];   // (E, E)
    const float* x   = (const float*)d_in[2];   // (B, S, E)
    const float* gw  = (const float*)d_in[3];   // (E, E)
    float* outp = (float*)d_out;
    char* ws = (char*)d_ws;

    size_t off = 0;
    unsigned short* x_bf    = (unsigned short*)(ws + off); off += (size_t)TOK*EMB*2;     // 16 MB
    unsigned short* wqkv_bf = (unsigned short*)(ws + off); off += (size_t)3*EMB*EMB*2;   // 6 MB
    unsigned short* wout_bf = (unsigned short*)(ws + off); off += (size_t)EMB*EMB*2;     // 2 MB
    unsigned short* gate_bf = (unsigned short*)(ws + off); off += (size_t)EMB*EMB*2;     // 2 MB
    unsigned short* qkv_bf  = (unsigned short*)(ws + off); off += (size_t)TOK*3*EMB*2;   // 48 MB
    unsigned short* vT_bf   = (unsigned short*)(ws + off); off += (size_t)NB*EMB*SQ*2;   // 16 MB
    float*          sc_f32  = (float*)(ws + off);          off += (size_t)NB*SQ*SQ*4;    // 64 MB
    // total 154 MB. Aliases (lifetimes disjoint, all launches sequential on one stream):
    unsigned short* attn_bf = qkv_bf;                        // qkv dead after K2; attn live K3->K4 (32 MB)
    unsigned short* ao_bf   = x_bf;                          // x dead after K1; ao live K4->K5 (16 MB)
    unsigned short* out_bf  = qkv_bf + (size_t)NB*SQ*SQ;     // qkv[32MB:48MB], live K5->K6 (16 MB)
    float*          out_f32 = sc_f32;                        // sc dead after K3; live K5->K6 (32 MB)

    // K0: converts (fold 1/sqrt(64)=0.125 into q-rows of w_qkv — exact pow2 scale)
    convert_kernel<<<dim3(TOK*EMB/4/256), dim3(256), 0, stream>>>(x, x_bf, TOK*EMB/4, 1.0f);
    convert_kernel<<<dim3(EMB*EMB/4/256), dim3(256), 0, stream>>>(rot, wqkv_bf, EMB*EMB/4, 0.125f);
    convert_kernel<<<dim3(2*EMB*EMB/4/256), dim3(256), 0, stream>>>(rot + EMB*EMB, wqkv_bf + EMB*EMB, 2*EMB*EMB/4, 1.0f);
    convert_kernel<<<dim3(EMB*EMB/4/256), dim3(256), 0, stream>>>(ent, wout_bf, EMB*EMB/4, 1.0f);
    convert_kernel<<<dim3(EMB*EMB/4/256), dim3(256), 0, stream>>>(gw, gate_bf, EMB*EMB/4, 1.0f);

    // K1: qkv = x @ w_qkv^T   (8192 x 3072, K=1024) -> bf16
    gemm_nt<0><<<dim3(TOK/128, 3*EMB/128, 1), dim3(256), 0, stream>>>(
        x_bf, wqkv_bf, qkv_bf, nullptr, nullptr,
        TOK, 3*EMB, EMB, EMB, EMB, 3*EMB, 0, 0, 0);

    // transpose v -> vT (per batch E x S)
    transpose_v<<<dim3(EMB/32, SQ/32, NB), dim3(32, 32), 0, stream>>>(qkv_bf, vT_bf);

    // K2: scores = q @ k^T per batch (2048 x 2048, K=1024) -> fp32
    gemm_nt<1><<<dim3(SQ/128, SQ/128, NB), dim3(256), 0, stream>>>(
        qkv_bf, qkv_bf + EMB, sc_f32, nullptr, nullptr,
        SQ, SQ, EMB, 3*EMB, 3*EMB, SQ,
        (long)SQ*3*EMB, (long)SQ*3*EMB, (long)SQ*SQ);

    // K3: softmax rows (fp32 in, bf16 out)
    softmax_kernel<<<dim3(NB*SQ), dim3(256), 0, stream>>>(sc_f32, attn_bf);

    // K4: attn_out = attn @ v per batch (2048 x 1024, K=2048); B = vT (NT form)
    gemm_nt<0><<<dim3(SQ/128, EMB/128, NB), dim3(256), 0, stream>>>(
        attn_bf, vT_bf, ao_bf, nullptr, nullptr,
        SQ, EMB, SQ, SQ, SQ, EMB,
        (long)SQ*SQ, (long)EMB*SQ, (long)SQ*EMB);

    // K5: out = attn_out @ w_out^T (8192 x 1024, K=1024) -> bf16 + fp32
    gemm_nt<3><<<dim3(TOK/128, EMB/128, 1), dim3(256), 0, stream>>>(
        ao_bf, wout_bf, out_bf, nullptr, out_f32,
        TOK, EMB, EMB, EMB, EMB, EMB, 0, 0, 0);

    // K6: result = sigmoid(out @ gate_w^T) * out_f32 -> fp32 d_out
    gemm_nt<2><<<dim3(TOK/128, EMB/128, 1), dim3(256), 0, stream>>>(
        out_bf, gate_bf, nullptr, out_f32, outp,
        TOK, EMB, EMB, EMB, EMB, EMB, 0, 0, 0);
}

// Round 3
// 380.093 us; speedup vs baseline: 1.0154x; 1.0154x over previous
//
#include <hip/hip_runtime.h>
#include <math.h>

#define EMB 1024
#define NB 4
#define SQ 2048
#define TOK (NB*SQ)   // 8192

typedef __attribute__((ext_vector_type(8))) short bhalf8;   // 8 bf16 in 4 VGPRs
typedef __attribute__((ext_vector_type(4))) float f32x4;

__device__ __forceinline__ unsigned short f32_to_bf16(float f) {
    unsigned int u = __float_as_uint(f);
    u += 0x7FFFu + ((u >> 16) & 1u);       // round-to-nearest-even
    return (unsigned short)(u >> 16);
}
__device__ __forceinline__ float bf16_to_f32(unsigned short h) {
    return __uint_as_float(((unsigned int)h) << 16);
}

// ---------------- fp32 -> bf16 conversion ----------------
__global__ __launch_bounds__(256) void convert_kernel(const float* __restrict__ src,
                                                      unsigned short* __restrict__ dst,
                                                      int n4, float scale) {
    int i = blockIdx.x * 256 + threadIdx.x;
    if (i >= n4) return;
    float4 v = ((const float4*)src)[i];
    ushort4 o;
    o.x = f32_to_bf16(v.x * scale);
    o.y = f32_to_bf16(v.y * scale);
    o.z = f32_to_bf16(v.z * scale);
    o.w = f32_to_bf16(v.w * scale);
    ((ushort4*)dst)[i] = o;
}

// all weights -> one contiguous bf16 region: [rot(3E^2, q-rows scaled 0.125), ent(E^2), gw(E^2)]
__global__ __launch_bounds__(256) void convert_weights_kernel(
    const float* __restrict__ rot, const float* __restrict__ ent,
    const float* __restrict__ gw, unsigned short* __restrict__ dst) {
    const int i = blockIdx.x * 256 + threadIdx.x;   // float4 index, total 5*E*E/4
    const int EE4 = EMB * EMB / 4;
    const float* src;
    float scale = 1.0f;
    int j = i;
    if (i < 3 * EE4) {
        src = rot;
        if (i < EE4) scale = 0.125f;                // 1/sqrt(64) folded into q-rows (exact pow2)
    } else if (i < 4 * EE4) { src = ent; j = i - 3 * EE4; }
    else                    { src = gw;  j = i - 4 * EE4; }
    float4 v = ((const float4*)src)[j];
    ushort4 o;
    o.x = f32_to_bf16(v.x * scale);
    o.y = f32_to_bf16(v.y * scale);
    o.z = f32_to_bf16(v.z * scale);
    o.w = f32_to_bf16(v.w * scale);
    ((ushort4*)dst)[i] = o;
}

// ---------------- async global->LDS 16B staging helper ----------------
__device__ __forceinline__ void async_load16(const unsigned short* gp, unsigned short* lp) {
    __builtin_amdgcn_global_load_lds(
        (const __attribute__((address_space(1))) unsigned int*)gp,
        (__attribute__((address_space(3))) unsigned int*)lp,
        16, 0, 0);
}

// ---------------- NT GEMM: C[m,n] = sum_k A[m,k]*B[n,k], bf16 in, fp32 acc ----------------
// LDS tile 128x32 halves. XOR-swizzled 16B colblocks: logical (row, cb) lives at
// physical colblock cb ^ ((row>>1)&3). Staging (wave-uniform base + lane*16B) realizes
// this by permuting WHICH global 16B chunk each lane fetches (same 64B segment ->
// coalescing unchanged). Fragment reads then hit all 8 bank phases 2-way (free, m136).
// MODE 0: store bf16 C
// MODE 1: store fp32 C
// MODE 2: g = sigmoid(acc); read fp32 Ofp; Fout = g * Ofp   (final gated output)
// MODE 3: store bf16 C AND fp32 Fout (same values)
template <int MODE>
__global__ __launch_bounds__(256) void gemm_nt(
    const unsigned short* __restrict__ A,
    const unsigned short* __restrict__ B,
    void* __restrict__ C,
    const float* __restrict__ Ofp,
    float* __restrict__ Fout,
    int M, int N, int K, int lda, int ldb, int ldc,
    long sA, long sB, long sC)
{
    __shared__ __align__(16) unsigned short As[128*32];   // 8 KB
    __shared__ __align__(16) unsigned short Bs[128*32];

    const int bz = blockIdx.z;
    const unsigned short* Ab = A + (long)bz * sA;
    const unsigned short* Bb = B + (long)bz * sB;
    const int bm = blockIdx.x * 128;
    const int bn = blockIdx.y * 128;
    const int t = threadIdx.x;
    const int w = t >> 6;        // wave 0..3
    const int l = t & 63;        // lane
    const int srow = l >> 2;     // staging row within 16-row group
    // swizzled staging colblock: lane l's LDS slot (block g*64+l) holds logical
    // (row = g*16 + (l>>2), cb = (l&3) ^ ((l>>3)&3))
    const int scol = (((l & 3) ^ ((l >> 3) & 3)) * 8);

    f32x4 zero = {0.f, 0.f, 0.f, 0.f};
    f32x4 acc[4][4];
    #pragma unroll
    for (int i = 0; i < 4; ++i)
        #pragma unroll
        for (int j = 0; j < 4; ++j) acc[i][j] = zero;

    const int wm = (w >> 1) * 64;   // wave's 64x64 sub-tile
    const int wn = (w & 1) * 64;
    const int fr = l & 15;          // fragment row (A) / col (B)
    // swizzled k-offset for fragment reads: logical cb = l>>4, row parity term
    // ((row>>1)&3) == ((l>>1)&3) since wm/mi*16 are multiples of 16. Lane-constant!
    const int kqs = (((l >> 4) ^ ((l >> 1) & 3)) * 8);

    const int nkt = K >> 5;
    for (int kt = 0; kt < nkt; ++kt) {
        const int k0 = kt << 5;
        __syncthreads();            // LDS consumers of previous tile done
        #pragma unroll
        for (int r = 0; r < 2; ++r) {
            const int rr = (r*4 + w) * 16 + srow;   // tile row 0..127
            async_load16(Ab + (long)(bm + rr) * lda + (k0 + scol), As + (r*4 + w) * 512);
            async_load16(Bb + (long)(bn + rr) * ldb + (k0 + scol), Bs + (r*4 + w) * 512);
        }
        __syncthreads();            // staging complete

        bhalf8 af[4], bfr[4];
        #pragma unroll
        for (int mi = 0; mi < 4; ++mi)
            af[mi] = *(const bhalf8*)(As + (wm + mi*16 + fr) * 32 + kqs);
        #pragma unroll
        for (int ni = 0; ni < 4; ++ni)
            bfr[ni] = *(const bhalf8*)(Bs + (wn + ni*16 + fr) * 32 + kqs);
        #pragma unroll
        for (int mi = 0; mi < 4; ++mi)
            #pragma unroll
            for (int ni = 0; ni < 4; ++ni)
                acc[mi][ni] = __builtin_amdgcn_mfma_f32_16x16x32_bf16(
                    af[mi], bfr[ni], acc[mi][ni], 0, 0, 0);
    }

    // C/D layout (m89-verified): col = lane&15, row = (lane>>4)*4 + reg
    const int crow = (l >> 4) * 4;
    const int ccol = l & 15;
    #pragma unroll
    for (int mi = 0; mi < 4; ++mi) {
        #pragma unroll
        for (int ni = 0; ni < 4; ++ni) {
            #pragma unroll
            for (int r = 0; r < 4; ++r) {
                const int gr = bm + wm + mi*16 + crow + r;
                const int gc = bn + wn + ni*16 + ccol;
                const float v = acc[mi][ni][r];
                const long idx = (long)gr * ldc + gc;
                if (MODE == 0) {
                    ((unsigned short*)C)[(long)bz*sC + idx] = f32_to_bf16(v);
                } else if (MODE == 1) {
                    ((float*)C)[(long)bz*sC + idx] = v;
                } else if (MODE == 2) {
                    const float o = Ofp[idx];
                    const float g = 1.0f / (1.0f + __expf(-v));
                    Fout[idx] = g * o;
                } else {
                    ((unsigned short*)C)[idx] = f32_to_bf16(v);
                    Fout[idx] = v;
                }
            }
        }
    }
}

// ---------------- row softmax: fp32 scores in, bf16 attn out (row len 2048) ----------------
__global__ __launch_bounds__(256) void softmax_kernel(const float* __restrict__ sc,
                                                      unsigned short* __restrict__ attn) {
    const long row = blockIdx.x;
    const float* p = sc + row * SQ;
    unsigned short* q = attn + row * SQ;
    const int t = threadIdx.x;
    const int w = t >> 6, l = t & 63;
    float4 a = ((const float4*)p)[2*t];
    float4 b = ((const float4*)p)[2*t + 1];
    float f[8] = {a.x, a.y, a.z, a.w, b.x, b.y, b.z, b.w};
    float m = -1e30f;
    #pragma unroll
    for (int j = 0; j < 8; ++j) m = fmaxf(m, f[j]);
    #pragma unroll
    for (int off = 32; off; off >>= 1) m = fmaxf(m, __shfl_xor(m, off));
    __shared__ float smax[4], ssum[4];
    if (l == 0) smax[w] = m;
    __syncthreads();
    m = fmaxf(fmaxf(smax[0], smax[1]), fmaxf(smax[2], smax[3]));
    float s = 0.f;
    #pragma unroll
    for (int j = 0; j < 8; ++j) { f[j] = __expf(f[j] - m); s += f[j]; }
    #pragma unroll
    for (int off = 32; off; off >>= 1) s += __shfl_xor(s, off);
    if (l == 0) ssum[w] = s;
    __syncthreads();
    const float inv = 1.0f / (ssum[0] + ssum[1] + ssum[2] + ssum[3]);
    union { bhalf8 v; unsigned short u[8]; } o;
    #pragma unroll
    for (int j = 0; j < 8; ++j) o.u[j] = f32_to_bf16(f[j] * inv);
    ((bhalf8*)q)[t] = o.v;
}

// ---------------- transpose v (per batch: (2048 x 1024, ld 3072) -> (1024 x 2048)) ----------------
__global__ void transpose_v(const unsigned short* __restrict__ qkv,
                            unsigned short* __restrict__ vT) {
    __shared__ unsigned short tile[32][33];
    const int b = blockIdx.z;
    const unsigned short* v = qkv + (long)b * SQ * (3*EMB) + 2*EMB;
    const int e = blockIdx.x * 32 + threadIdx.x;
    const int s = blockIdx.y * 32 + threadIdx.y;
    tile[threadIdx.y][threadIdx.x] = v[(long)s * (3*EMB) + e];
    __syncthreads();
    const int so = blockIdx.y * 32 + threadIdx.x;
    const int eo = blockIdx.x * 32 + threadIdx.y;
    vT[(long)b * EMB * SQ + (long)eo * SQ + so] = tile[threadIdx.x][threadIdx.y];
}

extern "C" void kernel_launch(void* const* d_in, const int* in_sizes, int n_in,
                              void* d_out, int out_size, void* d_ws, size_t ws_size,
                              hipStream_t stream) {
    const float* rot = (const float*)d_in[0];   // (3E, E) row-major
    const float* ent = (const float*)d_in[1];   // (E, E)
    const float* x   = (const float*)d_in[2];   // (B, S, E)
    const float* gw  = (const float*)d_in[3];   // (E, E)
    float* outp = (float*)d_out;
    char* ws = (char*)d_ws;

    size_t off = 0;
    unsigned short* x_bf    = (unsigned short*)(ws + off); off += (size_t)TOK*EMB*2;     // 16 MB
    unsigned short* wqkv_bf = (unsigned short*)(ws + off); off += (size_t)3*EMB*EMB*2;   // 6 MB
    unsigned short* wout_bf = (unsigned short*)(ws + off); off += (size_t)EMB*EMB*2;     // 2 MB
    unsigned short* gate_bf = (unsigned short*)(ws + off); off += (size_t)EMB*EMB*2;     // 2 MB
    unsigned short* qkv_bf  = (unsigned short*)(ws + off); off += (size_t)TOK*3*EMB*2;   // 48 MB
    unsigned short* vT_bf   = (unsigned short*)(ws + off); off += (size_t)NB*EMB*SQ*2;   // 16 MB
    float*          sc_f32  = (float*)(ws + off);          off += (size_t)NB*SQ*SQ*4;    // 64 MB
    // total 154 MB. Aliases (lifetimes disjoint, all launches sequential on one stream):
    unsigned short* attn_bf = qkv_bf;                        // qkv dead after K2; attn live K3->K4 (32 MB)
    unsigned short* ao_bf   = x_bf;                          // x dead after K1; ao live K4->K5 (16 MB)
    unsigned short* out_bf  = qkv_bf + (size_t)NB*SQ*SQ;     // qkv[32MB:48MB], live K5->K6 (16 MB)
    float*          out_f32 = sc_f32;                        // sc dead after K3; live K5->K6 (32 MB)

    // K0: converts (x; then all weights into the contiguous wqkv|wout|gate region)
    convert_kernel<<<dim3(TOK*EMB/4/256), dim3(256), 0, stream>>>(x, x_bf, TOK*EMB/4, 1.0f);
    convert_weights_kernel<<<dim3(5*EMB*EMB/4/256), dim3(256), 0, stream>>>(rot, ent, gw, wqkv_bf);

    // K1: qkv = x @ w_qkv^T   (8192 x 3072, K=1024) -> bf16
    gemm_nt<0><<<dim3(TOK/128, 3*EMB/128, 1), dim3(256), 0, stream>>>(
        x_bf, wqkv_bf, qkv_bf, nullptr, nullptr,
        TOK, 3*EMB, EMB, EMB, EMB, 3*EMB, 0, 0, 0);

    // transpose v -> vT (per batch E x S)
    transpose_v<<<dim3(EMB/32, SQ/32, NB), dim3(32, 32), 0, stream>>>(qkv_bf, vT_bf);

    // K2: scores = q @ k^T per batch (2048 x 2048, K=1024) -> fp32
    gemm_nt<1><<<dim3(SQ/128, SQ/128, NB), dim3(256), 0, stream>>>(
        qkv_bf, qkv_bf + EMB, sc_f32, nullptr, nullptr,
        SQ, SQ, EMB, 3*EMB, 3*EMB, SQ,
        (long)SQ*3*EMB, (long)SQ*3*EMB, (long)SQ*SQ);

    // K3: softmax rows (fp32 in, bf16 out)
    softmax_kernel<<<dim3(NB*SQ), dim3(256), 0, stream>>>(sc_f32, attn_bf);

    // K4: attn_out = attn @ v per batch (2048 x 1024, K=2048); B = vT (NT form)
    gemm_nt<0><<<dim3(SQ/128, EMB/128, NB), dim3(256), 0, stream>>>(
        attn_bf, vT_bf, ao_bf, nullptr, nullptr,
        SQ, EMB, SQ, SQ, SQ, EMB,
        (long)SQ*SQ, (long)EMB*SQ, (long)SQ*EMB);

    // K5: out = attn_out @ w_out^T (8192 x 1024, K=1024) -> bf16 + fp32
    gemm_nt<3><<<dim3(TOK/128, EMB/128, 1), dim3(256), 0, stream>>>(
        ao_bf, wout_bf, out_bf, nullptr, out_f32,
        TOK, EMB, EMB, EMB, EMB, EMB, 0, 0, 0);

    // K6: result = sigmoid(out @ gate_w^T) * out_f32 -> fp32 d_out
    gemm_nt<2><<<dim3(TOK/128, EMB/128, 1), dim3(256), 0, stream>>>(
        out_bf, gate_bf, nullptr, out_f32, outp,
        TOK, EMB, EMB, EMB, EMB, EMB, 0, 0, 0);
}

// Round 4
// 346.822 us; speedup vs baseline: 1.1128x; 1.0959x over previous
//
#include <hip/hip_runtime.h>
#include <math.h>

#define EMB 1024
#define NB 4
#define SQ 2048
#define TOK (NB*SQ)   // 8192

typedef __attribute__((ext_vector_type(8))) short bhalf8;   // 8 bf16 in 4 VGPRs
typedef __attribute__((ext_vector_type(4))) float f32x4;

__device__ __forceinline__ unsigned short f32_to_bf16(float f) {
    unsigned int u = __float_as_uint(f);
    u += 0x7FFFu + ((u >> 16) & 1u);       // round-to-nearest-even
    return (unsigned short)(u >> 16);
}
__device__ __forceinline__ float bf16_to_f32(unsigned short h) {
    return __uint_as_float(((unsigned int)h) << 16);
}

// ---------------- fp32 -> bf16 conversion ----------------
__global__ __launch_bounds__(256) void convert_kernel(const float* __restrict__ src,
                                                      unsigned short* __restrict__ dst,
                                                      int n4, float scale) {
    int i = blockIdx.x * 256 + threadIdx.x;
    if (i >= n4) return;
    float4 v = ((const float4*)src)[i];
    ushort4 o;
    o.x = f32_to_bf16(v.x * scale);
    o.y = f32_to_bf16(v.y * scale);
    o.z = f32_to_bf16(v.z * scale);
    o.w = f32_to_bf16(v.w * scale);
    ((ushort4*)dst)[i] = o;
}

// all weights -> one contiguous bf16 region: [rot(3E^2, q-rows scaled 0.125), ent(E^2), gw(E^2)]
__global__ __launch_bounds__(256) void convert_weights_kernel(
    const float* __restrict__ rot, const float* __restrict__ ent,
    const float* __restrict__ gw, unsigned short* __restrict__ dst) {
    const int i = blockIdx.x * 256 + threadIdx.x;   // float4 index, total 5*E*E/4
    const int EE4 = EMB * EMB / 4;
    const float* src;
    float scale = 1.0f;
    int j = i;
    if (i < 3 * EE4) {
        src = rot;
        if (i < EE4) scale = 0.125f;                // 1/sqrt(64) folded into q-rows (exact pow2)
    } else if (i < 4 * EE4) { src = ent; j = i - 3 * EE4; }
    else                    { src = gw;  j = i - 4 * EE4; }
    float4 v = ((const float4*)src)[j];
    ushort4 o;
    o.x = f32_to_bf16(v.x * scale);
    o.y = f32_to_bf16(v.y * scale);
    o.z = f32_to_bf16(v.z * scale);
    o.w = f32_to_bf16(v.w * scale);
    ((ushort4*)dst)[i] = o;
}

// ---------------- async global->LDS 16B staging helper ----------------
__device__ __forceinline__ void async_load16(const unsigned short* gp, unsigned short* lp) {
    __builtin_amdgcn_global_load_lds(
        (const __attribute__((address_space(1))) unsigned int*)gp,
        (__attribute__((address_space(3))) unsigned int*)lp,
        16, 0, 0);
}

// ---------------- NT GEMM: C[m,n] = sum_k A[m,k]*B[n,k], bf16 in, fp32 acc ----------------
// BK=64: LDS tile 128x64 halves (16 KB each, 32 KB total -> still >=4 blocks/CU LDS-limit).
// 32 MFMA + 16 ds_read_b128 + 8 global_load_lds per barrier-pair (2x the BK=32 version),
// halving barrier-drain count. XOR swizzle over 8 colblocks of 16 B: physical cb =
// logical cb ^ (row&7). Staging permutes lanes within each row's 128 B (coalescing
// unchanged); fragment-read xor term is lane-constant (two k-offsets, one per K-half);
// every wave LDS access hits all 8 bank phases evenly (conflict-free, verified R3).
// MODE 0: store bf16 C
// MODE 1: store fp32 C
// MODE 2: g = sigmoid(acc); read fp32 Ofp; Fout = g * Ofp   (final gated output)
// MODE 3: store bf16 C AND fp32 Fout (same values)
template <int MODE>
__global__ __launch_bounds__(256) void gemm_nt(
    const unsigned short* __restrict__ A,
    const unsigned short* __restrict__ B,
    void* __restrict__ C,
    const float* __restrict__ Ofp,
    float* __restrict__ Fout,
    int M, int N, int K, int lda, int ldb, int ldc,
    long sA, long sB, long sC)
{
    __shared__ __align__(16) unsigned short As[128*64];   // 16 KB
    __shared__ __align__(16) unsigned short Bs[128*64];

    const int bz = blockIdx.z;
    const unsigned short* Ab = A + (long)bz * sA;
    const unsigned short* Bb = B + (long)bz * sB;
    const int bm = blockIdx.x * 128;
    const int bn = blockIdx.y * 128;
    const int t = threadIdx.x;
    const int w = t >> 6;        // wave 0..3
    const int l = t & 63;        // lane
    // staging: wave-instr (r,w) covers 8 rows x 64 halves; lane l -> physical block
    // (row = base8 + (l>>3), pcb = l&7), which holds logical colblock pcb ^ (row&7):
    const int srow8 = l >> 3;                              // row within 8-row group
    const int scol  = (((l & 7) ^ ((l >> 3) & 7)) * 8);    // logical colblock * 8 halves

    f32x4 zero = {0.f, 0.f, 0.f, 0.f};
    f32x4 acc[4][4];
    #pragma unroll
    for (int i = 0; i < 4; ++i)
        #pragma unroll
        for (int j = 0; j < 4; ++j) acc[i][j] = zero;

    const int wm = (w >> 1) * 64;   // wave's 64x64 sub-tile
    const int wn = (w & 1) * 64;
    const int fr = l & 15;          // fragment row (A) / col (B)
    // fragment k-offsets (halves) for the two K=32 halves of the staged BK=64 tile.
    // logical cb = h*4 + (l>>4); row&7 == l&7 (16-row-aligned bases). Lane-constant.
    const int kqs0 = ((((l >> 4)    ) ^ (l & 7)) * 8);
    const int kqs1 = (((4 + (l >> 4)) ^ (l & 7)) * 8);

    const int nkt = K >> 6;
    for (int kt = 0; kt < nkt; ++kt) {
        const int k0 = kt << 6;
        __syncthreads();            // LDS consumers of previous tile done
        #pragma unroll
        for (int r = 0; r < 4; ++r) {
            const int rr = (r*4 + w) * 8 + srow8;   // tile row 0..127
            async_load16(Ab + (long)(bm + rr) * lda + (k0 + scol), As + (r*4 + w) * 512);
            async_load16(Bb + (long)(bn + rr) * ldb + (k0 + scol), Bs + (r*4 + w) * 512);
        }
        __syncthreads();            // staging complete

        #pragma unroll
        for (int h = 0; h < 2; ++h) {
            const int kq = h ? kqs1 : kqs0;
            bhalf8 af[4], bfr[4];
            #pragma unroll
            for (int mi = 0; mi < 4; ++mi)
                af[mi] = *(const bhalf8*)(As + (wm + mi*16 + fr) * 64 + kq);
            #pragma unroll
            for (int ni = 0; ni < 4; ++ni)
                bfr[ni] = *(const bhalf8*)(Bs + (wn + ni*16 + fr) * 64 + kq);
            #pragma unroll
            for (int mi = 0; mi < 4; ++mi)
                #pragma unroll
                for (int ni = 0; ni < 4; ++ni)
                    acc[mi][ni] = __builtin_amdgcn_mfma_f32_16x16x32_bf16(
                        af[mi], bfr[ni], acc[mi][ni], 0, 0, 0);
        }
    }

    // C/D layout (m89-verified): col = lane&15, row = (lane>>4)*4 + reg
    const int crow = (l >> 4) * 4;
    const int ccol = l & 15;
    #pragma unroll
    for (int mi = 0; mi < 4; ++mi) {
        #pragma unroll
        for (int ni = 0; ni < 4; ++ni) {
            #pragma unroll
            for (int r = 0; r < 4; ++r) {
                const int gr = bm + wm + mi*16 + crow + r;
                const int gc = bn + wn + ni*16 + ccol;
                const float v = acc[mi][ni][r];
                const long idx = (long)gr * ldc + gc;
                if (MODE == 0) {
                    ((unsigned short*)C)[(long)bz*sC + idx] = f32_to_bf16(v);
                } else if (MODE == 1) {
                    ((float*)C)[(long)bz*sC + idx] = v;
                } else if (MODE == 2) {
                    const float o = Ofp[idx];
                    const float g = 1.0f / (1.0f + __expf(-v));
                    Fout[idx] = g * o;
                } else {
                    ((unsigned short*)C)[idx] = f32_to_bf16(v);
                    Fout[idx] = v;
                }
            }
        }
    }
}

// ---------------- row softmax: fp32 scores in, bf16 attn out (row len 2048) ----------------
__global__ __launch_bounds__(256) void softmax_kernel(const float* __restrict__ sc,
                                                      unsigned short* __restrict__ attn) {
    const long row = blockIdx.x;
    const float* p = sc + row * SQ;
    unsigned short* q = attn + row * SQ;
    const int t = threadIdx.x;
    const int w = t >> 6, l = t & 63;
    float4 a = ((const float4*)p)[2*t];
    float4 b = ((const float4*)p)[2*t + 1];
    float f[8] = {a.x, a.y, a.z, a.w, b.x, b.y, b.z, b.w};
    float m = -1e30f;
    #pragma unroll
    for (int j = 0; j < 8; ++j) m = fmaxf(m, f[j]);
    #pragma unroll
    for (int off = 32; off; off >>= 1) m = fmaxf(m, __shfl_xor(m, off));
    __shared__ float smax[4], ssum[4];
    if (l == 0) smax[w] = m;
    __syncthreads();
    m = fmaxf(fmaxf(smax[0], smax[1]), fmaxf(smax[2], smax[3]));
    float s = 0.f;
    #pragma unroll
    for (int j = 0; j < 8; ++j) { f[j] = __expf(f[j] - m); s += f[j]; }
    #pragma unroll
    for (int off = 32; off; off >>= 1) s += __shfl_xor(s, off);
    if (l == 0) ssum[w] = s;
    __syncthreads();
    const float inv = 1.0f / (ssum[0] + ssum[1] + ssum[2] + ssum[3]);
    union { bhalf8 v; unsigned short u[8]; } o;
    #pragma unroll
    for (int j = 0; j < 8; ++j) o.u[j] = f32_to_bf16(f[j] * inv);
    ((bhalf8*)q)[t] = o.v;
}

// ---------------- transpose v (per batch: (2048 x 1024, ld 3072) -> (1024 x 2048)) ----------------
__global__ void transpose_v(const unsigned short* __restrict__ qkv,
                            unsigned short* __restrict__ vT) {
    __shared__ unsigned short tile[32][33];
    const int b = blockIdx.z;
    const unsigned short* v = qkv + (long)b * SQ * (3*EMB) + 2*EMB;
    const int e = blockIdx.x * 32 + threadIdx.x;
    const int s = blockIdx.y * 32 + threadIdx.y;
    tile[threadIdx.y][threadIdx.x] = v[(long)s * (3*EMB) + e];
    __syncthreads();
    const int so = blockIdx.y * 32 + threadIdx.x;
    const int eo = blockIdx.x * 32 + threadIdx.y;
    vT[(long)b * EMB * SQ + (long)eo * SQ + so] = tile[threadIdx.x][threadIdx.y];
}

extern "C" void kernel_launch(void* const* d_in, const int* in_sizes, int n_in,
                              void* d_out, int out_size, void* d_ws, size_t ws_size,
                              hipStream_t stream) {
    const float* rot = (const float*)d_in[0];   // (3E, E) row-major
    const float* ent = (const float*)d_in[1];   // (E, E)
    const float* x   = (const float*)d_in[2];   // (B, S, E)
    const float* gw  = (const float*)d_in[3];   // (E, E)
    float* outp = (float*)d_out;
    char* ws = (char*)d_ws;

    size_t off = 0;
    unsigned short* x_bf    = (unsigned short*)(ws + off); off += (size_t)TOK*EMB*2;     // 16 MB
    unsigned short* wqkv_bf = (unsigned short*)(ws + off); off += (size_t)3*EMB*EMB*2;   // 6 MB
    unsigned short* wout_bf = (unsigned short*)(ws + off); off += (size_t)EMB*EMB*2;     // 2 MB
    unsigned short* gate_bf = (unsigned short*)(ws + off); off += (size_t)EMB*EMB*2;     // 2 MB
    unsigned short* qkv_bf  = (unsigned short*)(ws + off); off += (size_t)TOK*3*EMB*2;   // 48 MB
    unsigned short* vT_bf   = (unsigned short*)(ws + off); off += (size_t)NB*EMB*SQ*2;   // 16 MB
    float*          sc_f32  = (float*)(ws + off);          off += (size_t)NB*SQ*SQ*4;    // 64 MB
    // total 154 MB. Aliases (lifetimes disjoint, all launches sequential on one stream):
    unsigned short* attn_bf = qkv_bf;                        // qkv dead after K2; attn live K3->K4 (32 MB)
    unsigned short* ao_bf   = x_bf;                          // x dead after K1; ao live K4->K5 (16 MB)
    unsigned short* out_bf  = qkv_bf + (size_t)NB*SQ*SQ;     // qkv[32MB:48MB], live K5->K6 (16 MB)
    float*          out_f32 = sc_f32;                        // sc dead after K3; live K5->K6 (32 MB)

    // K0: converts (x; then all weights into the contiguous wqkv|wout|gate region)
    convert_kernel<<<dim3(TOK*EMB/4/256), dim3(256), 0, stream>>>(x, x_bf, TOK*EMB/4, 1.0f);
    convert_weights_kernel<<<dim3(5*EMB*EMB/4/256), dim3(256), 0, stream>>>(rot, ent, gw, wqkv_bf);

    // K1: qkv = x @ w_qkv^T   (8192 x 3072, K=1024) -> bf16
    gemm_nt<0><<<dim3(TOK/128, 3*EMB/128, 1), dim3(256), 0, stream>>>(
        x_bf, wqkv_bf, qkv_bf, nullptr, nullptr,
        TOK, 3*EMB, EMB, EMB, EMB, 3*EMB, 0, 0, 0);

    // transpose v -> vT (per batch E x S)
    transpose_v<<<dim3(EMB/32, SQ/32, NB), dim3(32, 32), 0, stream>>>(qkv_bf, vT_bf);

    // K2: scores = q @ k^T per batch (2048 x 2048, K=1024) -> fp32
    gemm_nt<1><<<dim3(SQ/128, SQ/128, NB), dim3(256), 0, stream>>>(
        qkv_bf, qkv_bf + EMB, sc_f32, nullptr, nullptr,
        SQ, SQ, EMB, 3*EMB, 3*EMB, SQ,
        (long)SQ*3*EMB, (long)SQ*3*EMB, (long)SQ*SQ);

    // K3: softmax rows (fp32 in, bf16 out)
    softmax_kernel<<<dim3(NB*SQ), dim3(256), 0, stream>>>(sc_f32, attn_bf);

    // K4: attn_out = attn @ v per batch (2048 x 1024, K=2048); B = vT (NT form)
    gemm_nt<0><<<dim3(SQ/128, EMB/128, NB), dim3(256), 0, stream>>>(
        attn_bf, vT_bf, ao_bf, nullptr, nullptr,
        SQ, EMB, SQ, SQ, SQ, EMB,
        (long)SQ*SQ, (long)EMB*SQ, (long)SQ*EMB);

    // K5: out = attn_out @ w_out^T (8192 x 1024, K=1024) -> bf16 + fp32
    gemm_nt<3><<<dim3(TOK/128, EMB/128, 1), dim3(256), 0, stream>>>(
        ao_bf, wout_bf, out_bf, nullptr, out_f32,
        TOK, EMB, EMB, EMB, EMB, EMB, 0, 0, 0);

    // K6: result = sigmoid(out @ gate_w^T) * out_f32 -> fp32 d_out
    gemm_nt<2><<<dim3(TOK/128, EMB/128, 1), dim3(256), 0, stream>>>(
        out_bf, gate_bf, nullptr, out_f32, outp,
        TOK, EMB, EMB, EMB, EMB, EMB, 0, 0, 0);
}

// Round 5
// 324.653 us; speedup vs baseline: 1.1887x; 1.0683x over previous
//
#include <hip/hip_runtime.h>
#include <math.h>

#define EMB 1024
#define NB 4
#define SQ 2048
#define TOK (NB*SQ)   // 8192

typedef __attribute__((ext_vector_type(8))) short bhalf8;    // 8 bf16 (4 VGPRs)
typedef __attribute__((ext_vector_type(4))) float f32x4;
typedef __attribute__((ext_vector_type(16))) float f32x16;   // 32x32 accumulator

__device__ __forceinline__ unsigned short f32_to_bf16(float f) {
    unsigned int u = __float_as_uint(f);
    u += 0x7FFFu + ((u >> 16) & 1u);       // round-to-nearest-even
    return (unsigned short)(u >> 16);
}
__device__ __forceinline__ float bf16_to_f32(unsigned short h) {
    return __uint_as_float(((unsigned int)h) << 16);
}
__device__ __forceinline__ unsigned short f32_to_f16(float f) {
    union { _Float16 h; unsigned short u; } c; c.h = (_Float16)f; return c.u;
}
__device__ __forceinline__ float f16_to_f32(unsigned short u) {
    union { _Float16 h; unsigned short u; } c; c.u = u; return (float)c.h;
}

// ---------------- fused fp32 -> bf16 conversion: x (8192 blocks) + weights (5120) ----------------
// weights land contiguously: [rot(3E^2, q-rows scaled 0.125) | ent(E^2) | gw(E^2)]
__global__ __launch_bounds__(256) void convert_all_kernel(
    const float* __restrict__ x,  unsigned short* __restrict__ x_bf,
    const float* __restrict__ rot, const float* __restrict__ ent,
    const float* __restrict__ gw, unsigned short* __restrict__ w_bf) {
    const int EE4 = EMB * EMB / 4;
    const float* src;
    unsigned short* dst;
    float scale = 1.0f;
    int j;
    if (blockIdx.x < TOK*EMB/4/256) {
        src = x; dst = x_bf; j = blockIdx.x * 256 + threadIdx.x;
        float4 v = ((const float4*)src)[j];
        ushort4 o = { f32_to_bf16(v.x), f32_to_bf16(v.y), f32_to_bf16(v.z), f32_to_bf16(v.w) };
        ((ushort4*)dst)[j] = o;
        return;
    }
    const int i = (blockIdx.x - TOK*EMB/4/256) * 256 + threadIdx.x;   // over 5*EE4
    j = i; dst = w_bf;
    if (i < 3 * EE4) {
        src = rot;
        if (i < EE4) scale = 0.125f;                // 1/sqrt(64) folded into q-rows (exact pow2)
    } else if (i < 4 * EE4) { src = ent; j = i - 3 * EE4; }
    else                    { src = gw;  j = i - 4 * EE4; }
    float4 v = ((const float4*)src)[j];
    ushort4 o;
    o.x = f32_to_bf16(v.x * scale);
    o.y = f32_to_bf16(v.y * scale);
    o.z = f32_to_bf16(v.z * scale);
    o.w = f32_to_bf16(v.w * scale);
    ((ushort4*)dst)[i] = o;
}

// ---------------- async global->LDS 16B staging helper ----------------
__device__ __forceinline__ void async_load16(const unsigned short* gp, unsigned short* lp) {
    __builtin_amdgcn_global_load_lds(
        (const __attribute__((address_space(1))) unsigned int*)gp,
        (__attribute__((address_space(3))) unsigned int*)lp,
        16, 0, 0);
}

// ---------------- NT GEMM: C[m,n] = sum_k A[m,k]*B[n,k], bf16 in, fp32 acc ----------------
// BK=64, 128x128 tile, 32x32x16 MFMA (2x2 tiles/wave, 16 MFMA + 16 ds_read_b128 per kt).
// XOR swizzle over 8 colblocks of 16 B: physical cb = logical cb ^ (row&7). Staging
// permutes lanes within each row's 128 B (coalescing unchanged); fragment-read xor
// term (lane&7) is lane-constant; quarter-wave bank phases 2-way (conflict-free, R3/R4).
// MODE 0: store bf16 C
// MODE 1: store f16 C  (scores)
// MODE 2: g = sigmoid(acc); read fp32 Ofp; Fout = g * Ofp   (final gated output)
// MODE 3: store bf16 C AND fp32 Fout (same values)
template <int MODE>
__global__ __launch_bounds__(256) void gemm_nt(
    const unsigned short* __restrict__ A,
    const unsigned short* __restrict__ B,
    void* __restrict__ C,
    const float* __restrict__ Ofp,
    float* __restrict__ Fout,
    int M, int N, int K, int lda, int ldb, int ldc,
    long sA, long sB, long sC)
{
    __shared__ __align__(16) unsigned short As[128*64];   // 16 KB
    __shared__ __align__(16) unsigned short Bs[128*64];

    const int bz = blockIdx.z;
    const unsigned short* Ab = A + (long)bz * sA;
    const unsigned short* Bb = B + (long)bz * sB;
    const int bm = blockIdx.x * 128;
    const int bn = blockIdx.y * 128;
    const int t = threadIdx.x;
    const int w = t >> 6;        // wave 0..3
    const int l = t & 63;        // lane
    // staging: wave-instr (r,w) covers 8 rows x 64 halves; lane l -> physical block
    // (row = base8 + (l>>3), pcb = l&7), which holds logical colblock pcb ^ (row&7):
    const int srow8 = l >> 3;
    const int scol  = (((l & 7) ^ ((l >> 3) & 7)) * 8);

    f32x16 acc[2][2];
    #pragma unroll
    for (int i = 0; i < 2; ++i)
        #pragma unroll
        for (int j = 0; j < 2; ++j)
            #pragma unroll
            for (int r = 0; r < 16; ++r) acc[i][j][r] = 0.f;

    const int wm = (w >> 1) * 64;   // wave's 64x64 sub-tile
    const int wn = (w & 1) * 64;
    const int m31 = l & 31;         // fragment row (A) / col (B)
    const int half = l >> 5;
    // fragment k-offsets (halves) per K=16 step ks: logical cb = ks*2 + half;
    // row&7 == l&7 (rows 32-aligned). Lane-constant.
    int kq[4];
    #pragma unroll
    for (int ks = 0; ks < 4; ++ks)
        kq[ks] = (((ks*2 + half) ^ (l & 7)) * 8);

    const int nkt = K >> 6;
    for (int kt = 0; kt < nkt; ++kt) {
        const int k0 = kt << 6;
        __syncthreads();            // LDS consumers of previous tile done
        #pragma unroll
        for (int r = 0; r < 4; ++r) {
            const int rr = (r*4 + w) * 8 + srow8;   // tile row 0..127
            async_load16(Ab + (long)(bm + rr) * lda + (k0 + scol), As + (r*4 + w) * 512);
            async_load16(Bb + (long)(bn + rr) * ldb + (k0 + scol), Bs + (r*4 + w) * 512);
        }
        __syncthreads();            // staging complete

        #pragma unroll
        for (int ks = 0; ks < 4; ++ks) {
            bhalf8 af[2], bfr[2];
            #pragma unroll
            for (int mi = 0; mi < 2; ++mi)
                af[mi] = *(const bhalf8*)(As + (wm + mi*32 + m31) * 64 + kq[ks]);
            #pragma unroll
            for (int ni = 0; ni < 2; ++ni)
                bfr[ni] = *(const bhalf8*)(Bs + (wn + ni*32 + m31) * 64 + kq[ks]);
            #pragma unroll
            for (int mi = 0; mi < 2; ++mi)
                #pragma unroll
                for (int ni = 0; ni < 2; ++ni)
                    acc[mi][ni] = __builtin_amdgcn_mfma_f32_32x32x16_bf16(
                        af[mi], bfr[ni], acc[mi][ni], 0, 0, 0);
        }
    }

    // C/D layout 32x32 (m74/m101-verified): col = lane&31, row = (reg&3)+8*(reg>>2)+4*(lane>>5)
    const int ccol = m31;
    const int rbase = half * 4;
    #pragma unroll
    for (int mi = 0; mi < 2; ++mi) {
        #pragma unroll
        for (int ni = 0; ni < 2; ++ni) {
            #pragma unroll
            for (int r = 0; r < 16; ++r) {
                const int row = (r & 3) + 8 * (r >> 2) + rbase;
                const int gr = bm + wm + mi*32 + row;
                const int gc = bn + wn + ni*32 + ccol;
                const float v = acc[mi][ni][r];
                const long idx = (long)gr * ldc + gc;
                if (MODE == 0) {
                    ((unsigned short*)C)[(long)bz*sC + idx] = f32_to_bf16(v);
                } else if (MODE == 1) {
                    ((unsigned short*)C)[(long)bz*sC + idx] = f32_to_f16(v);
                } else if (MODE == 2) {
                    const float o = Ofp[idx];
                    const float g = 1.0f / (1.0f + __expf(-v));
                    Fout[idx] = g * o;
                } else {
                    ((unsigned short*)C)[idx] = f32_to_bf16(v);
                    Fout[idx] = v;
                }
            }
        }
    }
}

// ---------------- row softmax: f16 scores in, bf16 attn out (row len 2048) ----------------
__global__ __launch_bounds__(256) void softmax_kernel(const unsigned short* __restrict__ sc,
                                                      unsigned short* __restrict__ attn) {
    const long row = blockIdx.x;
    const unsigned short* p = sc + row * SQ;
    unsigned short* q = attn + row * SQ;
    const int t = threadIdx.x;
    const int w = t >> 6, l = t & 63;
    union { bhalf8 v; unsigned short u[8]; } in;
    in.v = ((const bhalf8*)p)[t];
    float f[8];
    float m = -1e30f;
    #pragma unroll
    for (int j = 0; j < 8; ++j) { f[j] = f16_to_f32(in.u[j]); m = fmaxf(m, f[j]); }
    #pragma unroll
    for (int off = 32; off; off >>= 1) m = fmaxf(m, __shfl_xor(m, off));
    __shared__ float smax[4], ssum[4];
    if (l == 0) smax[w] = m;
    __syncthreads();
    m = fmaxf(fmaxf(smax[0], smax[1]), fmaxf(smax[2], smax[3]));
    float s = 0.f;
    #pragma unroll
    for (int j = 0; j < 8; ++j) { f[j] = __expf(f[j] - m); s += f[j]; }
    #pragma unroll
    for (int off = 32; off; off >>= 1) s += __shfl_xor(s, off);
    if (l == 0) ssum[w] = s;
    __syncthreads();
    const float inv = 1.0f / (ssum[0] + ssum[1] + ssum[2] + ssum[3]);
    union { bhalf8 v; unsigned short u[8]; } o;
    #pragma unroll
    for (int j = 0; j < 8; ++j) o.u[j] = f32_to_bf16(f[j] * inv);
    ((bhalf8*)q)[t] = o.v;
}

// ---------------- transpose v (per batch: (2048 x 1024, ld 3072) -> (1024 x 2048)) ----------------
__global__ void transpose_v(const unsigned short* __restrict__ qkv,
                            unsigned short* __restrict__ vT) {
    __shared__ unsigned short tile[32][33];
    const int b = blockIdx.z;
    const unsigned short* v = qkv + (long)b * SQ * (3*EMB) + 2*EMB;
    const int e = blockIdx.x * 32 + threadIdx.x;
    const int s = blockIdx.y * 32 + threadIdx.y;
    tile[threadIdx.y][threadIdx.x] = v[(long)s * (3*EMB) + e];
    __syncthreads();
    const int so = blockIdx.y * 32 + threadIdx.x;
    const int eo = blockIdx.x * 32 + threadIdx.y;
    vT[(long)b * EMB * SQ + (long)eo * SQ + so] = tile[threadIdx.x][threadIdx.y];
}

extern "C" void kernel_launch(void* const* d_in, const int* in_sizes, int n_in,
                              void* d_out, int out_size, void* d_ws, size_t ws_size,
                              hipStream_t stream) {
    const float* rot = (const float*)d_in[0];   // (3E, E) row-major
    const float* ent = (const float*)d_in[1];   // (E, E)
    const float* x   = (const float*)d_in[2];   // (B, S, E)
    const float* gw  = (const float*)d_in[3];   // (E, E)
    float* outp = (float*)d_out;
    char* ws = (char*)d_ws;

    size_t off = 0;
    unsigned short* x_bf    = (unsigned short*)(ws + off); off += (size_t)TOK*EMB*2;     // 16 MB
    unsigned short* wqkv_bf = (unsigned short*)(ws + off); off += (size_t)3*EMB*EMB*2;   // 6 MB
    unsigned short* wout_bf = (unsigned short*)(ws + off); off += (size_t)EMB*EMB*2;     // 2 MB
    unsigned short* gate_bf = (unsigned short*)(ws + off); off += (size_t)EMB*EMB*2;     // 2 MB
    unsigned short* qkv_bf  = (unsigned short*)(ws + off); off += (size_t)TOK*3*EMB*2;   // 48 MB
    unsigned short* vT_bf   = (unsigned short*)(ws + off); off += (size_t)NB*EMB*SQ*2;   // 16 MB
    char*           scbase  = (char*)(ws + off);           off += (size_t)NB*SQ*SQ*4;    // 64 MB region
    // Aliases (lifetimes disjoint, all launches sequential on one stream):
    unsigned short* sc_f16  = (unsigned short*)scbase;       // scores f16, live K2->K3 (32 MB)
    float*          out_f32 = (float*)scbase;                // sc dead after K3; live K5->K6 (32 MB)
    unsigned short* attn_bf = qkv_bf;                        // qkv dead after K2; attn live K3->K4 (32 MB)
    unsigned short* ao_bf   = x_bf;                          // x dead after K1; ao live K4->K5 (16 MB)
    unsigned short* out_bf  = qkv_bf + (size_t)NB*SQ*SQ;     // qkv[32MB:48MB], live K5->K6 (16 MB)

    // K0: all converts in one launch (x + weights into contiguous wqkv|wout|gate)
    convert_all_kernel<<<dim3(TOK*EMB/4/256 + 5*EMB*EMB/4/256), dim3(256), 0, stream>>>(
        x, x_bf, rot, ent, gw, wqkv_bf);

    // K1: qkv = x @ w_qkv^T   (8192 x 3072, K=1024) -> bf16
    gemm_nt<0><<<dim3(TOK/128, 3*EMB/128, 1), dim3(256), 0, stream>>>(
        x_bf, wqkv_bf, qkv_bf, nullptr, nullptr,
        TOK, 3*EMB, EMB, EMB, EMB, 3*EMB, 0, 0, 0);

    // transpose v -> vT (per batch E x S)
    transpose_v<<<dim3(EMB/32, SQ/32, NB), dim3(32, 32), 0, stream>>>(qkv_bf, vT_bf);

    // K2: scores = q @ k^T per batch (2048 x 2048, K=1024) -> f16
    gemm_nt<1><<<dim3(SQ/128, SQ/128, NB), dim3(256), 0, stream>>>(
        qkv_bf, qkv_bf + EMB, sc_f16, nullptr, nullptr,
        SQ, SQ, EMB, 3*EMB, 3*EMB, SQ,
        (long)SQ*3*EMB, (long)SQ*3*EMB, (long)SQ*SQ);

    // K3: softmax rows (f16 in, bf16 out)
    softmax_kernel<<<dim3(NB*SQ), dim3(256), 0, stream>>>(sc_f16, attn_bf);

    // K4: attn_out = attn @ v per batch (2048 x 1024, K=2048); B = vT (NT form)
    gemm_nt<0><<<dim3(SQ/128, EMB/128, NB), dim3(256), 0, stream>>>(
        attn_bf, vT_bf, ao_bf, nullptr, nullptr,
        SQ, EMB, SQ, SQ, SQ, EMB,
        (long)SQ*SQ, (long)EMB*SQ, (long)SQ*EMB);

    // K5: out = attn_out @ w_out^T (8192 x 1024, K=1024) -> bf16 + fp32
    gemm_nt<3><<<dim3(TOK/128, EMB/128, 1), dim3(256), 0, stream>>>(
        ao_bf, wout_bf, out_bf, nullptr, out_f32,
        TOK, EMB, EMB, EMB, EMB, EMB, 0, 0, 0);

    // K6: result = sigmoid(out @ gate_w^T) * out_f32 -> fp32 d_out
    gemm_nt<2><<<dim3(TOK/128, EMB/128, 1), dim3(256), 0, stream>>>(
        out_bf, gate_bf, nullptr, out_f32, outp,
        TOK, EMB, EMB, EMB, EMB, EMB, 0, 0, 0);
}

// Round 6
// 317.674 us; speedup vs baseline: 1.2149x; 1.0220x over previous
//
#include <hip/hip_runtime.h>
#include <math.h>

#define EMB 1024
#define NB 4
#define SQ 2048
#define TOK (NB*SQ)   // 8192

typedef __attribute__((ext_vector_type(8))) short bhalf8;   // 8 bf16 (4 VGPRs)
typedef __attribute__((ext_vector_type(4))) float f32x4;

__device__ __forceinline__ unsigned short f32_to_bf16(float f) {
    unsigned int u = __float_as_uint(f);
    u += 0x7FFFu + ((u >> 16) & 1u);       // round-to-nearest-even
    return (unsigned short)(u >> 16);
}
__device__ __forceinline__ float bf16_to_f32(unsigned short h) {
    return __uint_as_float(((unsigned int)h) << 16);
}
__device__ __forceinline__ unsigned short f32_to_f16(float f) {
    union { _Float16 h; unsigned short u; } c; c.h = (_Float16)f; return c.u;
}
__device__ __forceinline__ float f16_to_f32(unsigned short u) {
    union { _Float16 h; unsigned short u; } c; c.u = u; return (float)c.h;
}

// ---------------- fused fp32 -> bf16 conversion: x (8192 blocks) + weights (5120) ----------------
// weights land contiguously: [rot(3E^2, q-rows scaled 0.125) | ent(E^2) | gw(E^2)]
__global__ __launch_bounds__(256) void convert_all_kernel(
    const float* __restrict__ x,  unsigned short* __restrict__ x_bf,
    const float* __restrict__ rot, const float* __restrict__ ent,
    const float* __restrict__ gw, unsigned short* __restrict__ w_bf) {
    const int EE4 = EMB * EMB / 4;
    const float* src;
    unsigned short* dst;
    float scale = 1.0f;
    int j;
    if (blockIdx.x < TOK*EMB/4/256) {
        src = x; dst = x_bf; j = blockIdx.x * 256 + threadIdx.x;
        float4 v = ((const float4*)src)[j];
        ushort4 o = { f32_to_bf16(v.x), f32_to_bf16(v.y), f32_to_bf16(v.z), f32_to_bf16(v.w) };
        ((ushort4*)dst)[j] = o;
        return;
    }
    const int i = (blockIdx.x - TOK*EMB/4/256) * 256 + threadIdx.x;   // over 5*EE4
    j = i; dst = w_bf;
    if (i < 3 * EE4) {
        src = rot;
        if (i < EE4) scale = 0.125f;                // 1/sqrt(64) folded into q-rows (exact pow2)
    } else if (i < 4 * EE4) { src = ent; j = i - 3 * EE4; }
    else                    { src = gw;  j = i - 4 * EE4; }
    float4 v = ((const float4*)src)[j];
    ushort4 o;
    o.x = f32_to_bf16(v.x * scale);
    o.y = f32_to_bf16(v.y * scale);
    o.z = f32_to_bf16(v.z * scale);
    o.w = f32_to_bf16(v.w * scale);
    ((ushort4*)dst)[i] = o;
}

// ---------------- async global->LDS 16B staging helper ----------------
__device__ __forceinline__ void async_load16(const unsigned short* gp, unsigned short* lp) {
    __builtin_amdgcn_global_load_lds(
        (const __attribute__((address_space(1))) unsigned int*)gp,
        (__attribute__((address_space(3))) unsigned int*)lp,
        16, 0, 0);
}

// ---------------- NT GEMM: C[m,n] = sum_k A[m,k]*B[n,k], bf16 in, fp32 acc ----------------
// BK=64, 128x128 tile, 16x16x32 MFMA (4x4 tiles/wave). This exact inner loop measured
// ZERO LDS bank conflicts (R4); the 32x32 variant measured 4 cyc/ds_read (R5) - reverted.
// XOR swizzle over 8 colblocks of 16 B: physical cb = logical cb ^ (row&7). Staging
// permutes lanes within each row's 128 B (coalescing unchanged); fragment-read xor
// term is lane-constant (two k-offsets, one per K=32 half).
// MODE 0: store bf16 C
// MODE 1: store f16 C  (scores)
// MODE 2: g = sigmoid(acc); read bf16 Obf; Fout = g * Obf   (final gated output)
template <int MODE>
__global__ __launch_bounds__(256) void gemm_nt(
    const unsigned short* __restrict__ A,
    const unsigned short* __restrict__ B,
    void* __restrict__ C,
    const unsigned short* __restrict__ Obf,
    float* __restrict__ Fout,
    int M, int N, int K, int lda, int ldb, int ldc,
    long sA, long sB, long sC)
{
    __shared__ __align__(16) unsigned short As[128*64];   // 16 KB
    __shared__ __align__(16) unsigned short Bs[128*64];

    const int bz = blockIdx.z;
    const unsigned short* Ab = A + (long)bz * sA;
    const unsigned short* Bb = B + (long)bz * sB;
    const int bm = blockIdx.x * 128;
    const int bn = blockIdx.y * 128;
    const int t = threadIdx.x;
    const int w = t >> 6;        // wave 0..3
    const int l = t & 63;        // lane
    // staging: wave-instr (r,w) covers 8 rows x 64 halves; lane l -> physical block
    // (row = base8 + (l>>3), pcb = l&7), which holds logical colblock pcb ^ (row&7):
    const int srow8 = l >> 3;
    const int scol  = (((l & 7) ^ ((l >> 3) & 7)) * 8);

    f32x4 zero = {0.f, 0.f, 0.f, 0.f};
    f32x4 acc[4][4];
    #pragma unroll
    for (int i = 0; i < 4; ++i)
        #pragma unroll
        for (int j = 0; j < 4; ++j) acc[i][j] = zero;

    const int wm = (w >> 1) * 64;   // wave's 64x64 sub-tile
    const int wn = (w & 1) * 64;
    const int fr = l & 15;          // fragment row (A) / col (B)
    // fragment k-offsets (halves) for the two K=32 halves of the staged BK=64 tile.
    // logical cb = h*4 + (l>>4); row&7 == l&7 (16-row-aligned bases). Lane-constant.
    const int kqs0 = ((((l >> 4)    ) ^ (l & 7)) * 8);
    const int kqs1 = (((4 + (l >> 4)) ^ (l & 7)) * 8);

    const int nkt = K >> 6;
    for (int kt = 0; kt < nkt; ++kt) {
        const int k0 = kt << 6;
        __syncthreads();            // LDS consumers of previous tile done
        #pragma unroll
        for (int r = 0; r < 4; ++r) {
            const int rr = (r*4 + w) * 8 + srow8;   // tile row 0..127
            async_load16(Ab + (long)(bm + rr) * lda + (k0 + scol), As + (r*4 + w) * 512);
            async_load16(Bb + (long)(bn + rr) * ldb + (k0 + scol), Bs + (r*4 + w) * 512);
        }
        __syncthreads();            // staging complete

        #pragma unroll
        for (int h = 0; h < 2; ++h) {
            const int kq = h ? kqs1 : kqs0;
            bhalf8 af[4], bfr[4];
            #pragma unroll
            for (int mi = 0; mi < 4; ++mi)
                af[mi] = *(const bhalf8*)(As + (wm + mi*16 + fr) * 64 + kq);
            #pragma unroll
            for (int ni = 0; ni < 4; ++ni)
                bfr[ni] = *(const bhalf8*)(Bs + (wn + ni*16 + fr) * 64 + kq);
            #pragma unroll
            for (int mi = 0; mi < 4; ++mi)
                #pragma unroll
                for (int ni = 0; ni < 4; ++ni)
                    acc[mi][ni] = __builtin_amdgcn_mfma_f32_16x16x32_bf16(
                        af[mi], bfr[ni], acc[mi][ni], 0, 0, 0);
        }
    }

    // C/D layout (m89-verified): col = lane&15, row = (lane>>4)*4 + reg
    const int crow = (l >> 4) * 4;
    const int ccol = l & 15;
    #pragma unroll
    for (int mi = 0; mi < 4; ++mi) {
        #pragma unroll
        for (int ni = 0; ni < 4; ++ni) {
            #pragma unroll
            for (int r = 0; r < 4; ++r) {
                const int gr = bm + wm + mi*16 + crow + r;
                const int gc = bn + wn + ni*16 + ccol;
                const float v = acc[mi][ni][r];
                const long idx = (long)gr * ldc + gc;
                if (MODE == 0) {
                    ((unsigned short*)C)[(long)bz*sC + idx] = f32_to_bf16(v);
                } else if (MODE == 1) {
                    ((unsigned short*)C)[(long)bz*sC + idx] = f32_to_f16(v);
                } else {
                    const float o = bf16_to_f32(Obf[idx]);
                    const float g = 1.0f / (1.0f + __expf(-v));
                    Fout[idx] = g * o;
                }
            }
        }
    }
}

// ---------------- row softmax: f16 scores in, bf16 attn out (row len 2048) ----------------
__global__ __launch_bounds__(256) void softmax_kernel(const unsigned short* __restrict__ sc,
                                                      unsigned short* __restrict__ attn) {
    const long row = blockIdx.x;
    const unsigned short* p = sc + row * SQ;
    unsigned short* q = attn + row * SQ;
    const int t = threadIdx.x;
    const int w = t >> 6, l = t & 63;
    union { bhalf8 v; unsigned short u[8]; } in;
    in.v = ((const bhalf8*)p)[t];
    float f[8];
    float m = -1e30f;
    #pragma unroll
    for (int j = 0; j < 8; ++j) { f[j] = f16_to_f32(in.u[j]); m = fmaxf(m, f[j]); }
    #pragma unroll
    for (int off = 32; off; off >>= 1) m = fmaxf(m, __shfl_xor(m, off));
    __shared__ float smax[4], ssum[4];
    if (l == 0) smax[w] = m;
    __syncthreads();
    m = fmaxf(fmaxf(smax[0], smax[1]), fmaxf(smax[2], smax[3]));
    float s = 0.f;
    #pragma unroll
    for (int j = 0; j < 8; ++j) { f[j] = __expf(f[j] - m); s += f[j]; }
    #pragma unroll
    for (int off = 32; off; off >>= 1) s += __shfl_xor(s, off);
    if (l == 0) ssum[w] = s;
    __syncthreads();
    const float inv = 1.0f / (ssum[0] + ssum[1] + ssum[2] + ssum[3]);
    union { bhalf8 v; unsigned short u[8]; } o;
    #pragma unroll
    for (int j = 0; j < 8; ++j) o.u[j] = f32_to_bf16(f[j] * inv);
    ((bhalf8*)q)[t] = o.v;
}

// ---------------- transpose v (per batch: (2048 x 1024, ld 3072) -> (1024 x 2048)) ----------------
__global__ void transpose_v(const unsigned short* __restrict__ qkv,
                            unsigned short* __restrict__ vT) {
    __shared__ unsigned short tile[32][33];
    const int b = blockIdx.z;
    const unsigned short* v = qkv + (long)b * SQ * (3*EMB) + 2*EMB;
    const int e = blockIdx.x * 32 + threadIdx.x;
    const int s = blockIdx.y * 32 + threadIdx.y;
    tile[threadIdx.y][threadIdx.x] = v[(long)s * (3*EMB) + e];
    __syncthreads();
    const int so = blockIdx.y * 32 + threadIdx.x;
    const int eo = blockIdx.x * 32 + threadIdx.y;
    vT[(long)b * EMB * SQ + (long)eo * SQ + so] = tile[threadIdx.x][threadIdx.y];
}

extern "C" void kernel_launch(void* const* d_in, const int* in_sizes, int n_in,
                              void* d_out, int out_size, void* d_ws, size_t ws_size,
                              hipStream_t stream) {
    const float* rot = (const float*)d_in[0];   // (3E, E) row-major
    const float* ent = (const float*)d_in[1];   // (E, E)
    const float* x   = (const float*)d_in[2];   // (B, S, E)
    const float* gw  = (const float*)d_in[3];   // (E, E)
    float* outp = (float*)d_out;
    char* ws = (char*)d_ws;

    size_t off = 0;
    unsigned short* x_bf    = (unsigned short*)(ws + off); off += (size_t)TOK*EMB*2;     // 16 MB
    unsigned short* wqkv_bf = (unsigned short*)(ws + off); off += (size_t)3*EMB*EMB*2;   // 6 MB
    unsigned short* wout_bf = (unsigned short*)(ws + off); off += (size_t)EMB*EMB*2;     // 2 MB
    unsigned short* gate_bf = (unsigned short*)(ws + off); off += (size_t)EMB*EMB*2;     // 2 MB
    unsigned short* qkv_bf  = (unsigned short*)(ws + off); off += (size_t)TOK*3*EMB*2;   // 48 MB
    unsigned short* vT_bf   = (unsigned short*)(ws + off); off += (size_t)NB*EMB*SQ*2;   // 16 MB
    unsigned short* sc_f16  = (unsigned short*)(ws + off); off += (size_t)NB*SQ*SQ*2;    // 32 MB
    // Aliases (lifetimes disjoint, all launches sequential on one stream):
    unsigned short* attn_bf = qkv_bf;                        // qkv dead after K2; attn live K3->K4 (32 MB)
    unsigned short* ao_bf   = x_bf;                          // x dead after K1; ao live K4->K5 (16 MB)
    unsigned short* out_bf  = qkv_bf + (size_t)NB*SQ*SQ;     // qkv[32MB:48MB], live K5->K6 (16 MB)

    // K0: all converts in one launch (x + weights into contiguous wqkv|wout|gate)
    convert_all_kernel<<<dim3(TOK*EMB/4/256 + 5*EMB*EMB/4/256), dim3(256), 0, stream>>>(
        x, x_bf, rot, ent, gw, wqkv_bf);

    // K1: qkv = x @ w_qkv^T   (8192 x 3072, K=1024) -> bf16
    gemm_nt<0><<<dim3(TOK/128, 3*EMB/128, 1), dim3(256), 0, stream>>>(
        x_bf, wqkv_bf, qkv_bf, nullptr, nullptr,
        TOK, 3*EMB, EMB, EMB, EMB, 3*EMB, 0, 0, 0);

    // transpose v -> vT (per batch E x S)
    transpose_v<<<dim3(EMB/32, SQ/32, NB), dim3(32, 32), 0, stream>>>(qkv_bf, vT_bf);

    // K2: scores = q @ k^T per batch (2048 x 2048, K=1024) -> f16
    gemm_nt<1><<<dim3(SQ/128, SQ/128, NB), dim3(256), 0, stream>>>(
        qkv_bf, qkv_bf + EMB, sc_f16, nullptr, nullptr,
        SQ, SQ, EMB, 3*EMB, 3*EMB, SQ,
        (long)SQ*3*EMB, (long)SQ*3*EMB, (long)SQ*SQ);

    // K3: softmax rows (f16 in, bf16 out)
    softmax_kernel<<<dim3(NB*SQ), dim3(256), 0, stream>>>(sc_f16, attn_bf);

    // K4: attn_out = attn @ v per batch (2048 x 1024, K=2048); B = vT (NT form)
    gemm_nt<0><<<dim3(SQ/128, EMB/128, NB), dim3(256), 0, stream>>>(
        attn_bf, vT_bf, ao_bf, nullptr, nullptr,
        SQ, EMB, SQ, SQ, SQ, EMB,
        (long)SQ*SQ, (long)EMB*SQ, (long)SQ*EMB);

    // K5: out = attn_out @ w_out^T (8192 x 1024, K=1024) -> bf16
    gemm_nt<0><<<dim3(TOK/128, EMB/128, 1), dim3(256), 0, stream>>>(
        ao_bf, wout_bf, out_bf, nullptr, nullptr,
        TOK, EMB, EMB, EMB, EMB, EMB, 0, 0, 0);

    // K6: result = sigmoid(out @ gate_w^T) * out_bf -> fp32 d_out
    gemm_nt<2><<<dim3(TOK/128, EMB/128, 1), dim3(256), 0, stream>>>(
        out_bf, gate_bf, nullptr, out_bf, outp,
        TOK, EMB, EMB, EMB, EMB, EMB, 0, 0, 0);
}